// Round 1
// baseline (820.718 us; speedup 1.0000x reference)
//
#include <hip/hip_runtime.h>

#define HID 128
#define BM 128
#define LDPAD 136      // padded LDS leading dim (f32): 136*4=544B, 16B-multiple
#define LN_EPS 1e-5f

// ---------------- graph preprocessing ----------------

__global__ void k_init(int* __restrict__ cnt, int* __restrict__ cursor, int n) {
  int i = blockIdx.x * 256 + threadIdx.x;
  if (i < n) { cnt[i] = 0; cursor[i] = 0; }
}

__global__ void k_count(const int* __restrict__ dst, int* __restrict__ cnt, int E) {
  int e = blockIdx.x * 256 + threadIdx.x;
  if (e < E) atomicAdd(&cnt[dst[e]], 1);
}

__global__ void k_dinv(const int* __restrict__ cnt, float* __restrict__ dinv, int n) {
  int i = blockIdx.x * 256 + threadIdx.x;
  if (i < n) dinv[i] = rsqrtf((float)cnt[i] + 1.0f);   // +1 = self loop
}

// single-block exclusive scan: cnt[0..n) -> row_start[0..n)
__global__ void k_scan(const int* __restrict__ cnt, int* __restrict__ row_start, int n) {
  __shared__ int buf[1024];
  __shared__ int carry_sh;
  int tid = threadIdx.x;
  if (tid == 0) carry_sh = 0;
  __syncthreads();
  const int CH = 8;
  const int CHUNK = 1024 * CH;
  for (int base = 0; base < n; base += CHUNK) {
    int loc[CH];
    int s = 0;
    int i0 = base + tid * CH;
#pragma unroll
    for (int j = 0; j < CH; j++) {
      int i = i0 + j;
      int v = (i < n) ? cnt[i] : 0;
      loc[j] = v; s += v;
    }
    buf[tid] = s;
    __syncthreads();
    for (int off = 1; off < 1024; off <<= 1) {
      int t = (tid >= off) ? buf[tid - off] : 0;
      __syncthreads();
      buf[tid] += t;
      __syncthreads();
    }
    int ex = carry_sh + buf[tid] - s;   // exclusive prefix of this thread's first elem
#pragma unroll
    for (int j = 0; j < CH; j++) {
      int i = i0 + j;
      if (i < n) row_start[i] = ex;
      ex += loc[j];
    }
    int total = buf[1023];
    __syncthreads();
    if (tid == 0) carry_sh += total;
    __syncthreads();
  }
}

__global__ void k_scatter(const int* __restrict__ src, const int* __restrict__ dst,
                          const int* __restrict__ row_start, int* __restrict__ cursor,
                          const float* __restrict__ dinv,
                          int* __restrict__ col, float* __restrict__ ew, int E) {
  int e = blockIdx.x * 256 + threadIdx.x;
  if (e < E) {
    int d = dst[e], s = src[e];
    int pos = row_start[d] + atomicAdd(&cursor[d], 1);
    col[pos] = s;
    ew[pos] = dinv[s] * dinv[d];
  }
}

// ---------------- aggregation: s = D^-1/2 (A+I) D^-1/2 x ----------------
// one wave per node, lane = float2 of the 128-wide row
__global__ void k_agg(const float* __restrict__ x, const int* __restrict__ row_start,
                      const int* __restrict__ cnt, const float* __restrict__ dinv,
                      const int* __restrict__ col, const float* __restrict__ ew,
                      float* __restrict__ s_out, int n) {
  int node = blockIdx.x * 4 + (threadIdx.x >> 6);
  if (node >= n) return;
  int lane = threadIdx.x & 63;
  float dv = dinv[node];
  float2 v = reinterpret_cast<const float2*>(x + (size_t)node * HID)[lane];
  float2 acc;
  acc.x = dv * dv * v.x;
  acc.y = dv * dv * v.y;
  int start = row_start[node];
  int m = cnt[node];
  for (int e = 0; e < m; e++) {
    int sidx = col[start + e];
    float w = ew[start + e];
    float2 sv = reinterpret_cast<const float2*>(x + (size_t)sidx * HID)[lane];
    acc.x = fmaf(w, sv.x, acc.x);
    acc.y = fmaf(w, sv.y, acc.y);
  }
  reinterpret_cast<float2*>(s_out + (size_t)node * HID)[lane] = acc;
}

// ---------------- f32 GEMM pieces ----------------

__device__ __forceinline__ void stage_w(float* dst_lds, const float* __restrict__ w, int tid) {
  // 128x128 f32 -> LDS [128][LDPAD]
#pragma unroll
  for (int p = 0; p < 16; p++) {
    int idx = p * 1024 + tid * 4;
    int row = idx >> 7, c = idx & 127;
    float4 v = *reinterpret_cast<const float4*>(w + row * HID + c);
    *reinterpret_cast<float4*>(dst_lds + row * LDPAD + c) = v;
  }
}

__device__ __forceinline__ void stage_tile(float* dst_lds, const float* __restrict__ src,
                                           int r0, int nrows, int tid) {
#pragma unroll
  for (int p = 0; p < 16; p++) {
    int idx = p * 1024 + tid * 4;
    int row = idx >> 7, c = idx & 127;
    int gr = r0 + row;
    float4 v = make_float4(0.f, 0.f, 0.f, 0.f);
    if (gr < nrows) v = *reinterpret_cast<const float4*>(src + (size_t)gr * HID + c);
    *reinterpret_cast<float4*>(dst_lds + row * LDPAD + c) = v;
  }
}

__device__ __forceinline__ void mac_128(const float* As, const float* Ws,
                                        int ty, int tx, float acc[8][8]) {
  const float* arow = As + ty * 8 * LDPAD;
  const float* wcol = Ws + tx * 8;
#pragma unroll 2
  for (int k = 0; k < 128; k++) {
    float a[8];
#pragma unroll
    for (int i = 0; i < 8; i++) a[i] = arow[i * LDPAD + k];
    float4 w0 = *reinterpret_cast<const float4*>(wcol + k * LDPAD);
    float4 w1 = *reinterpret_cast<const float4*>(wcol + k * LDPAD + 4);
    float w[8] = {w0.x, w0.y, w0.z, w0.w, w1.x, w1.y, w1.z, w1.w};
#pragma unroll
    for (int i = 0; i < 8; i++)
#pragma unroll
      for (int j = 0; j < 8; j++) acc[i][j] = fmaf(a[i], w[j], acc[i][j]);
  }
}

// x0 = x @ W + b
__global__ void __launch_bounds__(256, 1)
k_gemm_in(const float* __restrict__ A, const float* __restrict__ W,
          const float* __restrict__ bias, float* __restrict__ C, int nrows) {
  extern __shared__ float lds[];
  float* As = lds;
  float* Ws = lds + BM * LDPAD;
  int tid = threadIdx.x;
  int r0 = blockIdx.x * BM;
  stage_w(Ws, W, tid);
  stage_tile(As, A, r0, nrows, tid);
  __syncthreads();
  int tx = tid & 15, ty = tid >> 4;
  float acc[8][8];
#pragma unroll
  for (int i = 0; i < 8; i++)
#pragma unroll
    for (int j = 0; j < 8; j++) acc[i][j] = 0.f;
  mac_128(As, Ws, ty, tx, acc);

  float4 b0 = *reinterpret_cast<const float4*>(bias + tx * 8);
  float4 b1 = *reinterpret_cast<const float4*>(bias + tx * 8 + 4);
  float b[8] = {b0.x, b0.y, b0.z, b0.w, b1.x, b1.y, b1.z, b1.w};
#pragma unroll
  for (int i = 0; i < 8; i++) {
    int gr = r0 + ty * 8 + i;
    if (gr < nrows) {
      float4 o0 = make_float4(acc[i][0] + b[0], acc[i][1] + b[1], acc[i][2] + b[2], acc[i][3] + b[3]);
      float4 o1 = make_float4(acc[i][4] + b[4], acc[i][5] + b[5], acc[i][6] + b[6], acc[i][7] + b[7]);
      *reinterpret_cast<float4*>(C + (size_t)gr * HID + tx * 8) = o0;
      *reinterpret_cast<float4*>(C + (size_t)gr * HID + tx * 8 + 4) = o1;
    }
  }
}

// x_new = relu(LN(s@Wc + x@Wl + bc + bl)); x <- x_new (in place); out (+)= x_new
__global__ void __launch_bounds__(256, 1)
k_layer(const float* __restrict__ Sbuf, float* __restrict__ Xbuf,
        const float* __restrict__ Wc, const float* __restrict__ Wl,
        const float* __restrict__ bc, const float* __restrict__ bl,
        const float* __restrict__ g, const float* __restrict__ bb,
        float* __restrict__ out, int nrows, int first) {
  extern __shared__ float lds[];
  float* As = lds;
  float* Ws = lds + BM * LDPAD;
  int tid = threadIdx.x;
  int r0 = blockIdx.x * BM;
  int tx = tid & 15, ty = tid >> 4;
  float acc[8][8];
#pragma unroll
  for (int i = 0; i < 8; i++)
#pragma unroll
    for (int j = 0; j < 8; j++) acc[i][j] = 0.f;

  // pass 1: s @ Wc
  stage_w(Ws, Wc, tid);
  stage_tile(As, Sbuf, r0, nrows, tid);
  __syncthreads();
  mac_128(As, Ws, ty, tx, acc);
  __syncthreads();
  // pass 2: x @ Wl
  stage_w(Ws, Wl, tid);
  stage_tile(As, Xbuf, r0, nrows, tid);
  __syncthreads();
  mac_128(As, Ws, ty, tx, acc);

  // epilogue: bias + LayerNorm + relu + JK accumulate
  float bias[8], gg[8], bbv[8];
  {
    float4 c0 = *reinterpret_cast<const float4*>(bc + tx * 8);
    float4 c1 = *reinterpret_cast<const float4*>(bc + tx * 8 + 4);
    float4 l0 = *reinterpret_cast<const float4*>(bl + tx * 8);
    float4 l1 = *reinterpret_cast<const float4*>(bl + tx * 8 + 4);
    bias[0] = c0.x + l0.x; bias[1] = c0.y + l0.y; bias[2] = c0.z + l0.z; bias[3] = c0.w + l0.w;
    bias[4] = c1.x + l1.x; bias[5] = c1.y + l1.y; bias[6] = c1.z + l1.z; bias[7] = c1.w + l1.w;
    float4 g0 = *reinterpret_cast<const float4*>(g + tx * 8);
    float4 g1 = *reinterpret_cast<const float4*>(g + tx * 8 + 4);
    gg[0] = g0.x; gg[1] = g0.y; gg[2] = g0.z; gg[3] = g0.w;
    gg[4] = g1.x; gg[5] = g1.y; gg[6] = g1.z; gg[7] = g1.w;
    float4 q0 = *reinterpret_cast<const float4*>(bb + tx * 8);
    float4 q1 = *reinterpret_cast<const float4*>(bb + tx * 8 + 4);
    bbv[0] = q0.x; bbv[1] = q0.y; bbv[2] = q0.z; bbv[3] = q0.w;
    bbv[4] = q1.x; bbv[5] = q1.y; bbv[6] = q1.z; bbv[7] = q1.w;
  }
  const float inv = 1.0f / 128.0f;
#pragma unroll
  for (int i = 0; i < 8; i++) {
    float sum = 0.f, sq = 0.f;
#pragma unroll
    for (int j = 0; j < 8; j++) {
      float v = acc[i][j] + bias[j];
      acc[i][j] = v;
      sum += v;
      sq = fmaf(v, v, sq);
    }
    // reduce across the 16 threads (consecutive lanes) sharing this row
#pragma unroll
    for (int m = 1; m < 16; m <<= 1) {
      sum += __shfl_xor(sum, m);
      sq += __shfl_xor(sq, m);
    }
    float mean = sum * inv;
    float var = sq * inv - mean * mean;
    float rstd = rsqrtf(var + LN_EPS);
    int gr = r0 + ty * 8 + i;
    if (gr < nrows) {
      float o[8];
#pragma unroll
      for (int j = 0; j < 8; j++) {
        float v = (acc[i][j] - mean) * rstd * gg[j] + bbv[j];
        o[j] = fmaxf(v, 0.f);
      }
      float4 o0 = make_float4(o[0], o[1], o[2], o[3]);
      float4 o1 = make_float4(o[4], o[5], o[6], o[7]);
      float* xp = Xbuf + (size_t)gr * HID + tx * 8;
      *reinterpret_cast<float4*>(xp) = o0;
      *reinterpret_cast<float4*>(xp + 4) = o1;
      float* op = out + (size_t)gr * HID + tx * 8;
      if (first) {
        *reinterpret_cast<float4*>(op) = o0;
        *reinterpret_cast<float4*>(op + 4) = o1;
      } else {
        float4 p0 = *reinterpret_cast<const float4*>(op);
        float4 p1 = *reinterpret_cast<const float4*>(op + 4);
        p0.x += o[0]; p0.y += o[1]; p0.z += o[2]; p0.w += o[3];
        p1.x += o[4]; p1.y += o[5]; p1.z += o[6]; p1.w += o[7];
        *reinterpret_cast<float4*>(op) = p0;
        *reinterpret_cast<float4*>(op + 4) = p1;
      }
    }
  }
}

// ---------------- launcher ----------------

extern "C" void kernel_launch(void* const* d_in, const int* in_sizes, int n_in,
                              void* d_out, int out_size, void* d_ws, size_t ws_size,
                              hipStream_t stream) {
  const float* x_in     = (const float*)d_in[0];
  const int*   edge     = (const int*)d_in[1];
  const float* lin_in_w = (const float*)d_in[2];
  const float* lin_in_b = (const float*)d_in[3];
  const float* conv_w   = (const float*)d_in[4];
  const float* conv_b   = (const float*)d_in[5];
  const float* lin_w    = (const float*)d_in[6];
  const float* lin_b    = (const float*)d_in[7];
  const float* ln_g     = (const float*)d_in[8];
  const float* ln_b     = (const float*)d_in[9];

  int N = in_sizes[0] / HID;
  int E = in_sizes[1] / 2;
  int L = in_sizes[4] / (HID * HID);
  const int* src = edge;
  const int* dst = edge + E;

  char* ws = (char*)d_ws;
  size_t off = 0;
  auto alloc = [&](size_t bytes) -> void* {
    void* p = (void*)(ws + off);
    off += (bytes + 255) & ~(size_t)255;
    return p;
  };
  int*   cnt       = (int*)alloc((size_t)N * 4);
  int*   cursor    = (int*)alloc((size_t)N * 4);
  int*   row_start = (int*)alloc((size_t)N * 4);
  float* dinv      = (float*)alloc((size_t)N * 4);
  int*   col       = (int*)alloc((size_t)E * 4);
  float* ew        = (float*)alloc((size_t)E * 4);
  float* xbuf      = (float*)alloc((size_t)N * HID * 4);
  float* sbuf      = (float*)alloc((size_t)N * HID * 4);
  (void)ws_size; (void)n_in; (void)out_size;

  int nb_n = (N + 255) / 256;
  int nb_e = (E + 255) / 256;
  int nb_r = (N + BM - 1) / BM;
  size_t shmem = (size_t)(BM + 128) * LDPAD * 4;

  k_init<<<nb_n, 256, 0, stream>>>(cnt, cursor, N);
  k_count<<<nb_e, 256, 0, stream>>>(dst, cnt, E);
  k_dinv<<<nb_n, 256, 0, stream>>>(cnt, dinv, N);
  k_scan<<<1, 1024, 0, stream>>>(cnt, row_start, N);
  k_scatter<<<nb_e, 256, 0, stream>>>(src, dst, row_start, cursor, dinv, col, ew, E);

  k_gemm_in<<<nb_r, 256, shmem, stream>>>(x_in, lin_in_w, lin_in_b, xbuf, N);

  for (int i = 0; i < L; i++) {
    k_agg<<<(N + 3) / 4, 256, 0, stream>>>(xbuf, row_start, cnt, dinv, col, ew, sbuf, N);
    k_layer<<<nb_r, 256, shmem, stream>>>(sbuf, xbuf,
        conv_w + (size_t)i * HID * HID, lin_w + (size_t)i * HID * HID,
        conv_b + (size_t)i * HID, lin_b + (size_t)i * HID,
        ln_g + (size_t)i * HID, ln_b + (size_t)i * HID,
        (float*)d_out, N, (i == 0) ? 1 : 0);
  }
}

// Round 2
// 503.555 us; speedup vs baseline: 1.6298x; 1.6298x over previous
//
#include <hip/hip_runtime.h>

#define HID 128
#define LN_EPS 1e-5f

typedef __attribute__((ext_vector_type(8))) short bf16x8;
typedef __attribute__((ext_vector_type(4))) float f32x4;

__device__ __forceinline__ ushort f2bf(float v) {
  union { float f; uint u; } x; x.f = v;
  uint r = x.u + 0x7fffu + ((x.u >> 16) & 1u);   // RNE
  return (ushort)(r >> 16);
}
__device__ __forceinline__ float bf2f(ushort u) {
  union { uint u; float f; } x; x.u = (uint)u << 16; return x.f;
}

// ---------------- graph preprocessing ----------------

__global__ void k_init(int* __restrict__ cnt, int* __restrict__ cursor, int n) {
  int i = blockIdx.x * 256 + threadIdx.x;
  if (i < n) { cnt[i] = 0; cursor[i] = 0; }
}

__global__ void k_count(const int* __restrict__ dst, int* __restrict__ cnt, int E) {
  int e = blockIdx.x * 256 + threadIdx.x;
  if (e < E) atomicAdd(&cnt[dst[e]], 1);
}

__global__ void k_dinv(const int* __restrict__ cnt, float* __restrict__ dinv, int n) {
  int i = blockIdx.x * 256 + threadIdx.x;
  if (i < n) dinv[i] = rsqrtf((float)cnt[i] + 1.0f);   // +1 = self loop
}

// hierarchical exclusive scan of cnt -> row_start (512 elems per block)
__global__ void k_bsum(const int* __restrict__ cnt, int* __restrict__ bsum, int n) {
  __shared__ int red[256];
  int b = blockIdx.x, t = threadIdx.x;
  int i = b * 512 + t * 2;
  int s = ((i < n) ? cnt[i] : 0) + ((i + 1 < n) ? cnt[i + 1] : 0);
  red[t] = s;
  __syncthreads();
  for (int off = 128; off > 0; off >>= 1) {
    if (t < off) red[t] += red[t + off];
    __syncthreads();
  }
  if (t == 0) bsum[b] = red[0];
}

__global__ void k_bscan(int* __restrict__ bsum, int nb) {
  __shared__ int buf[1024];
  int t = threadIdx.x;
  int v = (t < nb) ? bsum[t] : 0;
  buf[t] = v;
  __syncthreads();
  for (int off = 1; off < 1024; off <<= 1) {
    int u = (t >= off) ? buf[t - off] : 0;
    __syncthreads();
    buf[t] += u;
    __syncthreads();
  }
  if (t < nb) bsum[t] = buf[t] - v;   // exclusive
}

__global__ void k_rowstart(const int* __restrict__ cnt, const int* __restrict__ bsum,
                           int* __restrict__ row_start, int n) {
  __shared__ int buf[256];
  int b = blockIdx.x, t = threadIdx.x;
  int i = b * 512 + t * 2;
  int c0 = (i < n) ? cnt[i] : 0;
  int c1 = (i + 1 < n) ? cnt[i + 1] : 0;
  int s = c0 + c1;
  buf[t] = s;
  __syncthreads();
  int mine = s;
  for (int off = 1; off < 256; off <<= 1) {
    int u = (t >= off) ? buf[t - off] : 0;
    __syncthreads();
    buf[t] += u;
    __syncthreads();
  }
  int ex = buf[t] - mine + bsum[b];
  if (i < n) row_start[i] = ex;
  if (i + 1 < n) row_start[i + 1] = ex + c0;
}

__global__ void k_scatter(const int* __restrict__ src, const int* __restrict__ dst,
                          const int* __restrict__ row_start, int* __restrict__ cursor,
                          const float* __restrict__ dinv,
                          int* __restrict__ col, float* __restrict__ ew, int E) {
  int e = blockIdx.x * 256 + threadIdx.x;
  if (e < E) {
    int d = dst[e], s = src[e];
    int pos = row_start[d] + atomicAdd(&cursor[d], 1);
    col[pos] = s;
    ew[pos] = dinv[s] * dinv[d];
  }
}

// ---------------- weight prep: bf16 transpose ----------------
// wt_in[c*128 + k]        = lin_in_w[k][c]
// wt_l[l][c*256 + k2]     = k2<128 ? conv_w[l][k2][c] : lin_w[l][k2-128][c]
// bsum[l][c]              = conv_b[l][c] + lin_b[l][c]
__global__ void k_prep_w(const float* __restrict__ lin_in_w,
                         const float* __restrict__ conv_w, const float* __restrict__ lin_w,
                         const float* __restrict__ conv_b, const float* __restrict__ lin_b,
                         ushort* __restrict__ wt_in, ushort* __restrict__ wt_l,
                         float* __restrict__ bsum, int L) {
  int tid = blockIdx.x * 256 + threadIdx.x;
  int total = L * 128 * 256;
  if (tid < total) {
    int l = tid / (128 * 256);
    int r = tid - l * 128 * 256;
    int c = r >> 8;
    int k2 = r & 255;
    float v = (k2 < 128) ? conv_w[((size_t)l * 128 + k2) * 128 + c]
                         : lin_w[((size_t)l * 128 + (k2 - 128)) * 128 + c];
    wt_l[tid] = f2bf(v);
  }
  if (tid < 128 * 128) {
    int c = tid >> 7, k = tid & 127;
    wt_in[tid] = f2bf(lin_in_w[k * 128 + c]);
  }
  if (tid < L * 128) bsum[tid] = conv_b[tid] + lin_b[tid];
}

// ---------------- aggregation: s = D^-1/2 (A+I) D^-1/2 x  (bf16 in/out) ----------------
__global__ void k_agg(const ushort* __restrict__ X, const int* __restrict__ row_start,
                      const int* __restrict__ cnt, const float* __restrict__ dinv,
                      const int* __restrict__ col, const float* __restrict__ ew,
                      ushort* __restrict__ Sout, int n) {
  int node = blockIdx.x * 4 + (threadIdx.x >> 6);
  if (node >= n) return;
  int lane = threadIdx.x & 63;
  float dv = dinv[node];
  uint v = *reinterpret_cast<const uint*>(X + (size_t)node * HID + lane * 2);
  float ax = dv * dv * bf2f((ushort)(v & 0xffff));
  float ay = dv * dv * bf2f((ushort)(v >> 16));
  int start = row_start[node];
  int m = cnt[node];
  int e = 0;
  for (; e + 1 < m; e += 2) {
    int s0 = col[start + e], s1 = col[start + e + 1];
    float w0 = ew[start + e], w1 = ew[start + e + 1];
    uint u0 = *reinterpret_cast<const uint*>(X + (size_t)s0 * HID + lane * 2);
    uint u1 = *reinterpret_cast<const uint*>(X + (size_t)s1 * HID + lane * 2);
    ax = fmaf(w0, bf2f((ushort)(u0 & 0xffff)), ax);
    ay = fmaf(w0, bf2f((ushort)(u0 >> 16)), ay);
    ax = fmaf(w1, bf2f((ushort)(u1 & 0xffff)), ax);
    ay = fmaf(w1, bf2f((ushort)(u1 >> 16)), ay);
  }
  if (e < m) {
    int s0 = col[start + e];
    float w0 = ew[start + e];
    uint u0 = *reinterpret_cast<const uint*>(X + (size_t)s0 * HID + lane * 2);
    ax = fmaf(w0, bf2f((ushort)(u0 & 0xffff)), ax);
    ay = fmaf(w0, bf2f((ushort)(u0 >> 16)), ay);
  }
  uint o = (uint)f2bf(ax) | ((uint)f2bf(ay) << 16);
  *reinterpret_cast<uint*>(Sout + (size_t)node * HID + lane * 2) = o;
}

// ---------------- MFMA GEMM kernels ----------------
// per block: 4 waves, 16 rows each (64 rows/block); per wave: full 128 output cols.
// A-frag: lane holds A[r0 + (l&15)][ks*32 + (l>>4)*8 .. +7]  (bf16x8, 16B)
// B-frag: lane holds Wt[n*16 + (l&15)][ks*32 + (l>>4)*8 .. +7] (Wt = W^T)
// C: row=(l>>4)*4+q, col=n*16+(l&15)  -> LDS transpose for coalesced epilogue

__global__ void __launch_bounds__(256, 2)
k_gemm_in(const float* __restrict__ Xin, const ushort* __restrict__ Wt,
          const float* __restrict__ bias, ushort* __restrict__ Xout, int nrows) {
  __shared__ float lds[4 * 16 * 132];
  const int tid = threadIdx.x;
  const int wid = tid >> 6, lane = tid & 63;
  const int lr = lane & 15, lg = lane >> 4;
  const int r0 = blockIdx.x * 64 + wid * 16;
  const int arow = r0 + lr;
  const bool rowok = arow < nrows;

  bf16x8 a[4];
  {
    const float* xp = Xin + (size_t)arow * HID + lg * 8;
#pragma unroll
    for (int ks = 0; ks < 4; ks++) {
      bf16x8 t;
#pragma unroll
      for (int i = 0; i < 8; i++) t[i] = 0;
      if (rowok) {
        float4 u0 = *reinterpret_cast<const float4*>(xp + ks * 32);
        float4 u1 = *reinterpret_cast<const float4*>(xp + ks * 32 + 4);
        t[0] = (short)f2bf(u0.x); t[1] = (short)f2bf(u0.y);
        t[2] = (short)f2bf(u0.z); t[3] = (short)f2bf(u0.w);
        t[4] = (short)f2bf(u1.x); t[5] = (short)f2bf(u1.y);
        t[6] = (short)f2bf(u1.z); t[7] = (short)f2bf(u1.w);
      }
      a[ks] = t;
    }
  }

  f32x4 acc[8];
#pragma unroll
  for (int n = 0; n < 8; n++) acc[n] = f32x4{0.f, 0.f, 0.f, 0.f};

  const ushort* wbase = Wt + (size_t)lr * 128 + lg * 8;
#pragma unroll
  for (int n = 0; n < 8; n++) {
    const ushort* wp = wbase + n * 16 * 128;
#pragma unroll
    for (int ks = 0; ks < 4; ks++) {
      bf16x8 b = *reinterpret_cast<const bf16x8*>(wp + ks * 32);
      acc[n] = __builtin_amdgcn_mfma_f32_16x16x32_bf16(a[ks], b, acc[n], 0, 0, 0);
    }
  }

  float* T = lds + wid * (16 * 132);
#pragma unroll
  for (int n = 0; n < 8; n++)
#pragma unroll
    for (int q = 0; q < 4; q++)
      T[(lg * 4 + q) * 132 + n * 16 + lr] = acc[n][q];

  const int c0 = lg * 32;
  const float* Trow = T + lr * 132 + c0;
  const int orow = r0 + lr;
  if (orow < nrows) {
    ushort* xo = Xout + (size_t)orow * HID + c0;
    uint pk[16];
#pragma unroll
    for (int j = 0; j < 8; j++) {
      float4 t = *reinterpret_cast<const float4*>(Trow + j * 4);
      float4 b4 = *reinterpret_cast<const float4*>(bias + c0 + j * 4);
      float o0 = t.x + b4.x, o1 = t.y + b4.y, o2 = t.z + b4.z, o3 = t.w + b4.w;
      pk[j * 2 + 0] = (uint)f2bf(o0) | ((uint)f2bf(o1) << 16);
      pk[j * 2 + 1] = (uint)f2bf(o2) | ((uint)f2bf(o3) << 16);
    }
#pragma unroll
    for (int j = 0; j < 4; j++)
      *reinterpret_cast<uint4*>(xo + j * 8) =
          make_uint4(pk[j * 4 + 0], pk[j * 4 + 1], pk[j * 4 + 2], pk[j * 4 + 3]);
  }
}

__global__ void __launch_bounds__(256, 2)
k_layer(const ushort* __restrict__ S, ushort* __restrict__ X,
        const ushort* __restrict__ Wt, const float* __restrict__ bsum,
        const float* __restrict__ gamma, const float* __restrict__ beta,
        float* __restrict__ out, int nrows, int first) {
  __shared__ float lds[4 * 16 * 132];
  const int tid = threadIdx.x;
  const int wid = tid >> 6, lane = tid & 63;
  const int lr = lane & 15, lg = lane >> 4;
  const int r0 = blockIdx.x * 64 + wid * 16;
  const int arow = r0 + lr;
  const bool rowok = arow < nrows;

  bf16x8 a[8];
  {
    const ushort* sp = S + (size_t)arow * HID + lg * 8;
    const ushort* xp = X + (size_t)arow * HID + lg * 8;
    bf16x8 z;
#pragma unroll
    for (int i = 0; i < 8; i++) z[i] = 0;
#pragma unroll
    for (int ks = 0; ks < 4; ks++)
      a[ks] = rowok ? *reinterpret_cast<const bf16x8*>(sp + ks * 32) : z;
#pragma unroll
    for (int ks = 0; ks < 4; ks++)
      a[4 + ks] = rowok ? *reinterpret_cast<const bf16x8*>(xp + ks * 32) : z;
  }

  f32x4 acc[8];
#pragma unroll
  for (int n = 0; n < 8; n++) acc[n] = f32x4{0.f, 0.f, 0.f, 0.f};

  const ushort* wbase = Wt + (size_t)lr * 256 + lg * 8;
#pragma unroll
  for (int n = 0; n < 8; n++) {
    const ushort* wp = wbase + n * 16 * 256;
#pragma unroll
    for (int ks = 0; ks < 8; ks++) {
      bf16x8 b = *reinterpret_cast<const bf16x8*>(wp + ks * 32);
      acc[n] = __builtin_amdgcn_mfma_f32_16x16x32_bf16(a[ks], b, acc[n], 0, 0, 0);
    }
  }

  float* T = lds + wid * (16 * 132);
#pragma unroll
  for (int n = 0; n < 8; n++)
#pragma unroll
    for (int q = 0; q < 4; q++)
      T[(lg * 4 + q) * 132 + n * 16 + lr] = acc[n][q];

  // epilogue: lane handles row lr, cols [c0, c0+32)
  const int c0 = lg * 32;
  const float* Trow = T + lr * 132 + c0;
  float v[32];
  float sum = 0.f, sq = 0.f;
#pragma unroll
  for (int j = 0; j < 8; j++) {
    float4 t = *reinterpret_cast<const float4*>(Trow + j * 4);
    float4 b4 = *reinterpret_cast<const float4*>(bsum + c0 + j * 4);
    float x0 = t.x + b4.x, x1 = t.y + b4.y, x2 = t.z + b4.z, x3 = t.w + b4.w;
    v[j * 4 + 0] = x0; v[j * 4 + 1] = x1; v[j * 4 + 2] = x2; v[j * 4 + 3] = x3;
    sum += (x0 + x1) + (x2 + x3);
    sq = fmaf(x0, x0, sq); sq = fmaf(x1, x1, sq);
    sq = fmaf(x2, x2, sq); sq = fmaf(x3, x3, sq);
  }
  sum += __shfl_xor(sum, 16); sq += __shfl_xor(sq, 16);
  sum += __shfl_xor(sum, 32); sq += __shfl_xor(sq, 32);
  const float mean = sum * (1.f / 128.f);
  const float rstd = rsqrtf(sq * (1.f / 128.f) - mean * mean + LN_EPS);

  const int orow = r0 + lr;
  if (orow < nrows) {
    ushort* xo = X + (size_t)orow * HID + c0;
    float* op = out + (size_t)orow * HID + c0;
    uint pk[16];
#pragma unroll
    for (int j = 0; j < 8; j++) {
      float4 g4 = *reinterpret_cast<const float4*>(gamma + c0 + j * 4);
      float4 b4 = *reinterpret_cast<const float4*>(beta + c0 + j * 4);
      float o0 = fmaxf(fmaf((v[j * 4 + 0] - mean) * rstd, g4.x, b4.x), 0.f);
      float o1 = fmaxf(fmaf((v[j * 4 + 1] - mean) * rstd, g4.y, b4.y), 0.f);
      float o2 = fmaxf(fmaf((v[j * 4 + 2] - mean) * rstd, g4.z, b4.z), 0.f);
      float o3 = fmaxf(fmaf((v[j * 4 + 3] - mean) * rstd, g4.w, b4.w), 0.f);
      pk[j * 2 + 0] = (uint)f2bf(o0) | ((uint)f2bf(o1) << 16);
      pk[j * 2 + 1] = (uint)f2bf(o2) | ((uint)f2bf(o3) << 16);
      float4 w4 = make_float4(o0, o1, o2, o3);
      if (!first) {
        float4 p = *reinterpret_cast<const float4*>(op + j * 4);
        w4.x += p.x; w4.y += p.y; w4.z += p.z; w4.w += p.w;
      }
      *reinterpret_cast<float4*>(op + j * 4) = w4;
    }
#pragma unroll
    for (int j = 0; j < 4; j++)
      *reinterpret_cast<uint4*>(xo + j * 8) =
          make_uint4(pk[j * 4 + 0], pk[j * 4 + 1], pk[j * 4 + 2], pk[j * 4 + 3]);
  }
}

// ---------------- launcher ----------------

extern "C" void kernel_launch(void* const* d_in, const int* in_sizes, int n_in,
                              void* d_out, int out_size, void* d_ws, size_t ws_size,
                              hipStream_t stream) {
  const float* x_in     = (const float*)d_in[0];
  const int*   edge     = (const int*)d_in[1];
  const float* lin_in_w = (const float*)d_in[2];
  const float* lin_in_b = (const float*)d_in[3];
  const float* conv_w   = (const float*)d_in[4];
  const float* conv_b   = (const float*)d_in[5];
  const float* lin_w    = (const float*)d_in[6];
  const float* lin_b    = (const float*)d_in[7];
  const float* ln_g     = (const float*)d_in[8];
  const float* ln_b     = (const float*)d_in[9];

  int N = in_sizes[0] / HID;
  int E = in_sizes[1] / 2;
  int L = in_sizes[4] / (HID * HID);

  const int* src = edge;
  const int* dst = edge + E;

  char* ws = (char*)d_ws;
  size_t off = 0;
  auto alloc = [&](size_t bytes) -> void* {
    void* p = (void*)(ws + off);
    off += (bytes + 255) & ~(size_t)255;
    return p;
  };
  int*    cnt       = (int*)alloc((size_t)N * 4);
  int*    cursor    = (int*)alloc((size_t)N * 4);
  int*    row_start = (int*)alloc((size_t)N * 4);
  float*  dinv      = (float*)alloc((size_t)N * 4);
  int*    blocksum  = (int*)alloc(4096);
  int*    col       = (int*)alloc((size_t)E * 4);
  float*  ew        = (float*)alloc((size_t)E * 4);
  ushort* xbuf      = (ushort*)alloc((size_t)N * HID * 2);
  ushort* sbuf      = (ushort*)alloc((size_t)N * HID * 2);
  ushort* wt_in     = (ushort*)alloc((size_t)128 * 128 * 2);
  ushort* wt_l      = (ushort*)alloc((size_t)L * 128 * 256 * 2);
  float*  bsum      = (float*)alloc((size_t)L * 128 * 4);
  (void)ws_size; (void)n_in; (void)out_size;

  int nb_n = (N + 255) / 256;
  int nb_e = (E + 255) / 256;
  int nbs  = (N + 511) / 512;
  int nb_g = (N + 63) / 64;
  int nb_w = (L * 128 * 256 + 255) / 256;

  k_init<<<nb_n, 256, 0, stream>>>(cnt, cursor, N);
  k_count<<<nb_e, 256, 0, stream>>>(dst, cnt, E);
  k_dinv<<<nb_n, 256, 0, stream>>>(cnt, dinv, N);
  k_bsum<<<nbs, 256, 0, stream>>>(cnt, blocksum, N);
  k_bscan<<<1, 1024, 0, stream>>>(blocksum, nbs);
  k_rowstart<<<nbs, 256, 0, stream>>>(cnt, blocksum, row_start, N);
  k_scatter<<<nb_e, 256, 0, stream>>>(src, dst, row_start, cursor, dinv, col, ew, E);
  k_prep_w<<<nb_w, 256, 0, stream>>>(lin_in_w, conv_w, lin_w, conv_b, lin_b,
                                     wt_in, wt_l, bsum, L);

  k_gemm_in<<<nb_g, 256, 0, stream>>>(x_in, wt_in, lin_in_b, xbuf, N);

  for (int i = 0; i < L; i++) {
    k_agg<<<(N + 3) / 4, 256, 0, stream>>>(xbuf, row_start, cnt, dinv, col, ew, sbuf, N);
    k_layer<<<nb_g, 256, 0, stream>>>(sbuf, xbuf,
        wt_l + (size_t)i * 128 * 256, bsum + (size_t)i * 128,
        ln_g + (size_t)i * HID, ln_b + (size_t)i * HID,
        (float*)d_out, N, (i == 0) ? 1 : 0);
  }
}

// Round 4
// 407.849 us; speedup vs baseline: 2.0123x; 1.2347x over previous
//
#include <hip/hip_runtime.h>

#define HID 128
#define LN_EPS 1e-5f

typedef __attribute__((ext_vector_type(8))) short bf16x8;
typedef __attribute__((ext_vector_type(4))) float f32x4;

__device__ __forceinline__ ushort f2bf(float v) {
  union { float f; uint u; } x; x.f = v;
  uint r = x.u + 0x7fffu + ((x.u >> 16) & 1u);   // RNE
  return (ushort)(r >> 16);
}
__device__ __forceinline__ float bf2f(ushort u) {
  union { uint u; float f; } x; x.u = (uint)u << 16; return x.f;
}

// ---------------- graph preprocessing ----------------

__global__ void k_init(int* __restrict__ cnt, int* __restrict__ cursor, int n) {
  int i = blockIdx.x * 256 + threadIdx.x;
  if (i < n) { cnt[i] = 0; cursor[i] = 0; }
}

__global__ void k_count(const int* __restrict__ dst, int* __restrict__ cnt, int E) {
  int e = blockIdx.x * 256 + threadIdx.x;
  if (e < E) atomicAdd(&cnt[dst[e]], 1);
}

__global__ void k_dinv(const int* __restrict__ cnt, float* __restrict__ dinv, int n) {
  int i = blockIdx.x * 256 + threadIdx.x;
  if (i < n) dinv[i] = rsqrtf((float)cnt[i] + 1.0f);   // +1 = self loop
}

// hierarchical exclusive scan of cnt -> row_start (512 elems per block)
__global__ void k_bsum(const int* __restrict__ cnt, int* __restrict__ bsum, int n) {
  __shared__ int red[256];
  int b = blockIdx.x, t = threadIdx.x;
  int i = b * 512 + t * 2;
  int s = ((i < n) ? cnt[i] : 0) + ((i + 1 < n) ? cnt[i + 1] : 0);
  red[t] = s;
  __syncthreads();
  for (int off = 128; off > 0; off >>= 1) {
    if (t < off) red[t] += red[t + off];
    __syncthreads();
  }
  if (t == 0) bsum[b] = red[0];
}

__global__ void k_bscan(int* __restrict__ bsum, int nb) {
  __shared__ int buf[1024];
  int t = threadIdx.x;
  int v = (t < nb) ? bsum[t] : 0;
  buf[t] = v;
  __syncthreads();
  for (int off = 1; off < 1024; off <<= 1) {
    int u = (t >= off) ? buf[t - off] : 0;
    __syncthreads();
    buf[t] += u;
    __syncthreads();
  }
  if (t < nb) bsum[t] = buf[t] - v;   // exclusive
}

__global__ void k_rowstart(const int* __restrict__ cnt, const int* __restrict__ bsum,
                           int* __restrict__ row_start, int n) {
  __shared__ int buf[256];
  int b = blockIdx.x, t = threadIdx.x;
  int i = b * 512 + t * 2;
  int c0 = (i < n) ? cnt[i] : 0;
  int c1 = (i + 1 < n) ? cnt[i + 1] : 0;
  int s = c0 + c1;
  buf[t] = s;
  __syncthreads();
  int mine = s;
  for (int off = 1; off < 256; off <<= 1) {
    int u = (t >= off) ? buf[t - off] : 0;
    __syncthreads();
    buf[t] += u;
    __syncthreads();
  }
  int ex = buf[t] - mine + bsum[b];
  if (i < n) row_start[i] = ex;
  if (i + 1 < n) row_start[i + 1] = ex + c0;
}

// one 8B record per edge: {src, weight_bits} -> halves scattered-write line traffic
__global__ void k_scatter(const int* __restrict__ src, const int* __restrict__ dst,
                          const int* __restrict__ row_start, int* __restrict__ cursor,
                          const float* __restrict__ dinv,
                          uint2* __restrict__ rec, int E) {
  int e = blockIdx.x * 256 + threadIdx.x;
  if (e < E) {
    int d = dst[e], s = src[e];
    int pos = row_start[d] + atomicAdd(&cursor[d], 1);
    union { float f; uint u; } w; w.f = dinv[s] * dinv[d];
    rec[pos] = make_uint2((uint)s, w.u);
  }
}

// ---------------- weight prep: bf16, MFMA-fragment-ordered ----------------
// Fragment layout: frag[(n*KS + ks)*512 + lane*8 + j] = W^T-element for
//   k = ks*32 + (lane>>4)*8 + j,  col = n*16 + (lane&15)
// so each wave B-load is 64 lanes x 16B contiguous (coalesced dwordx4).
__global__ void k_prep_w(const float* __restrict__ lin_in_w,
                         const float* __restrict__ conv_w, const float* __restrict__ lin_w,
                         const float* __restrict__ conv_b, const float* __restrict__ lin_b,
                         ushort* __restrict__ wt_in, ushort* __restrict__ wt_l,
                         float* __restrict__ bsum, int L) {
  int tid = blockIdx.x * 256 + threadIdx.x;
  int total = L * 128 * 256;
  if (tid < total) {
    int l = tid >> 15;              // /32768
    int idx = tid & 32767;
    int n = idx >> 12;              // 8 col-blocks
    int r = idx & 4095;
    int ks = r >> 9;                // 8 k-steps (K=256)
    int r2 = r & 511;
    int lane = r2 >> 3;
    int j = r2 & 7;
    int k2 = ks * 32 + (lane >> 4) * 8 + j;
    int c = n * 16 + (lane & 15);
    float v = (k2 < 128) ? conv_w[((size_t)l * 128 + k2) * 128 + c]
                         : lin_w[((size_t)l * 128 + (k2 - 128)) * 128 + c];
    wt_l[tid] = f2bf(v);
  }
  if (tid < 128 * 128) {
    int n = tid >> 11;              // 8 col-blocks
    int r = tid & 2047;
    int ks = r >> 9;                // 4 k-steps (K=128)
    int r2 = r & 511;
    int lane = r2 >> 3;
    int j = r2 & 7;
    int k = ks * 32 + (lane >> 4) * 8 + j;
    int c = n * 16 + (lane & 15);
    wt_in[tid] = f2bf(lin_in_w[k * 128 + c]);
  }
  if (tid < L * 128) bsum[tid] = conv_b[tid] + lin_b[tid];
}

// ---------------- aggregation: s = D^-1/2 (A+I) D^-1/2 x  (bf16 in/out) ----------------
__global__ void k_agg(const ushort* __restrict__ X, const int* __restrict__ row_start,
                      const int* __restrict__ cnt, const float* __restrict__ dinv,
                      const uint2* __restrict__ rec, ushort* __restrict__ Sout, int n) {
  int node = blockIdx.x * 4 + (threadIdx.x >> 6);
  if (node >= n) return;
  int lane = threadIdx.x & 63;
  float dv = dinv[node];
  uint v = *reinterpret_cast<const uint*>(X + (size_t)node * HID + lane * 2);
  float ax = dv * dv * bf2f((ushort)(v & 0xffff));
  float ay = dv * dv * bf2f((ushort)(v >> 16));
  int start = row_start[node];
  int m = cnt[node];
  int e = 0;
  for (; e + 1 < m; e += 2) {
    uint2 r0 = rec[start + e];
    uint2 r1 = rec[start + e + 1];
    union { uint u; float f; } w0, w1; w0.u = r0.y; w1.u = r1.y;
    uint u0 = *reinterpret_cast<const uint*>(X + (size_t)r0.x * HID + lane * 2);
    uint u1 = *reinterpret_cast<const uint*>(X + (size_t)r1.x * HID + lane * 2);
    ax = fmaf(w0.f, bf2f((ushort)(u0 & 0xffff)), ax);
    ay = fmaf(w0.f, bf2f((ushort)(u0 >> 16)), ay);
    ax = fmaf(w1.f, bf2f((ushort)(u1 & 0xffff)), ax);
    ay = fmaf(w1.f, bf2f((ushort)(u1 >> 16)), ay);
  }
  if (e < m) {
    uint2 r0 = rec[start + e];
    union { uint u; float f; } w0; w0.u = r0.y;
    uint u0 = *reinterpret_cast<const uint*>(X + (size_t)r0.x * HID + lane * 2);
    ax = fmaf(w0.f, bf2f((ushort)(u0 & 0xffff)), ax);
    ay = fmaf(w0.f, bf2f((ushort)(u0 >> 16)), ay);
  }
  uint o = (uint)f2bf(ax) | ((uint)f2bf(ay) << 16);
  *reinterpret_cast<uint*>(Sout + (size_t)node * HID + lane * 2) = o;
}

// ---------------- MFMA GEMM kernels ----------------
// per block: 4 waves, 16 rows each; per wave: full 128 output cols.
// A-frag: lane holds A[r0 + (l&15)][ks*32 + (l>>4)*8 .. +7]
// B-frag: coalesced from fragment-ordered WtF
// C: row=(l>>4)*4+q, col=n*16+(l&15) -> LDS transpose for coalesced epilogue

__global__ void __launch_bounds__(256, 2)
k_gemm_in(const float* __restrict__ Xin, const ushort* __restrict__ WtF,
          const float* __restrict__ bias, ushort* __restrict__ Xout, int nrows) {
  __shared__ float lds[4 * 16 * 132];
  const int tid = threadIdx.x;
  const int wid = tid >> 6, lane = tid & 63;
  const int lr = lane & 15, lg = lane >> 4;
  const int r0 = blockIdx.x * 64 + wid * 16;
  const int arow = r0 + lr;
  const bool rowok = arow < nrows;

  bf16x8 a[4];
  {
    const float* xp = Xin + (size_t)arow * HID + lg * 8;
#pragma unroll
    for (int ks = 0; ks < 4; ks++) {
      bf16x8 t;
#pragma unroll
      for (int i = 0; i < 8; i++) t[i] = 0;
      if (rowok) {
        float4 u0 = *reinterpret_cast<const float4*>(xp + ks * 32);
        float4 u1 = *reinterpret_cast<const float4*>(xp + ks * 32 + 4);
        t[0] = (short)f2bf(u0.x); t[1] = (short)f2bf(u0.y);
        t[2] = (short)f2bf(u0.z); t[3] = (short)f2bf(u0.w);
        t[4] = (short)f2bf(u1.x); t[5] = (short)f2bf(u1.y);
        t[6] = (short)f2bf(u1.z); t[7] = (short)f2bf(u1.w);
      }
      a[ks] = t;
    }
  }

  f32x4 acc[8];
#pragma unroll
  for (int n = 0; n < 8; n++) acc[n] = f32x4{0.f, 0.f, 0.f, 0.f};

  const ushort* wb = WtF + lane * 8;
#pragma unroll
  for (int n = 0; n < 8; n++)
#pragma unroll
    for (int ks = 0; ks < 4; ks++) {
      bf16x8 b = *reinterpret_cast<const bf16x8*>(wb + (n * 4 + ks) * 512);
      acc[n] = __builtin_amdgcn_mfma_f32_16x16x32_bf16(a[ks], b, acc[n], 0, 0, 0);
    }

  float* T = lds + wid * (16 * 132);
#pragma unroll
  for (int n = 0; n < 8; n++)
#pragma unroll
    for (int q = 0; q < 4; q++)
      T[(lg * 4 + q) * 132 + n * 16 + lr] = acc[n][q];

  const int c0 = lg * 32;
  const float* Trow = T + lr * 132 + c0;
  const int orow = r0 + lr;
  if (orow < nrows) {
    ushort* xo = Xout + (size_t)orow * HID + c0;
    uint pk[16];
#pragma unroll
    for (int j = 0; j < 8; j++) {
      float4 t = *reinterpret_cast<const float4*>(Trow + j * 4);
      float4 b4 = *reinterpret_cast<const float4*>(bias + c0 + j * 4);
      float o0 = t.x + b4.x, o1 = t.y + b4.y, o2 = t.z + b4.z, o3 = t.w + b4.w;
      pk[j * 2 + 0] = (uint)f2bf(o0) | ((uint)f2bf(o1) << 16);
      pk[j * 2 + 1] = (uint)f2bf(o2) | ((uint)f2bf(o3) << 16);
    }
#pragma unroll
    for (int j = 0; j < 4; j++)
      *reinterpret_cast<uint4*>(xo + j * 8) =
          make_uint4(pk[j * 4 + 0], pk[j * 4 + 1], pk[j * 4 + 2], pk[j * 4 + 3]);
  }
}

__global__ void __launch_bounds__(256, 2)
k_layer(const ushort* __restrict__ S, const ushort* __restrict__ Xin,
        ushort* __restrict__ Xout,
        const ushort* __restrict__ WtF, const float* __restrict__ bsum,
        const float* __restrict__ gamma, const float* __restrict__ beta, int nrows) {
  __shared__ float lds[4 * 16 * 132];
  const int tid = threadIdx.x;
  const int wid = tid >> 6, lane = tid & 63;
  const int lr = lane & 15, lg = lane >> 4;
  const int r0 = blockIdx.x * 64 + wid * 16;
  const int arow = r0 + lr;
  const bool rowok = arow < nrows;

  bf16x8 a[8];
  {
    const ushort* sp = S + (size_t)arow * HID + lg * 8;
    const ushort* xp = Xin + (size_t)arow * HID + lg * 8;
    bf16x8 z;
#pragma unroll
    for (int i = 0; i < 8; i++) z[i] = 0;
#pragma unroll
    for (int ks = 0; ks < 4; ks++)
      a[ks] = rowok ? *reinterpret_cast<const bf16x8*>(sp + ks * 32) : z;
#pragma unroll
    for (int ks = 0; ks < 4; ks++)
      a[4 + ks] = rowok ? *reinterpret_cast<const bf16x8*>(xp + ks * 32) : z;
  }

  f32x4 acc[8];
#pragma unroll
  for (int n = 0; n < 8; n++) acc[n] = f32x4{0.f, 0.f, 0.f, 0.f};

  const ushort* wb = WtF + lane * 8;
#pragma unroll
  for (int n = 0; n < 8; n++)
#pragma unroll
    for (int ks = 0; ks < 8; ks++) {
      bf16x8 b = *reinterpret_cast<const bf16x8*>(wb + (n * 8 + ks) * 512);
      acc[n] = __builtin_amdgcn_mfma_f32_16x16x32_bf16(a[ks], b, acc[n], 0, 0, 0);
    }

  float* T = lds + wid * (16 * 132);
#pragma unroll
  for (int n = 0; n < 8; n++)
#pragma unroll
    for (int q = 0; q < 4; q++)
      T[(lg * 4 + q) * 132 + n * 16 + lr] = acc[n][q];

  // epilogue: lane handles row lr, cols [c0, c0+32)
  const int c0 = lg * 32;
  const float* Trow = T + lr * 132 + c0;
  float v[32];
  float sum = 0.f, sq = 0.f;
#pragma unroll
  for (int j = 0; j < 8; j++) {
    float4 t = *reinterpret_cast<const float4*>(Trow + j * 4);
    float4 b4 = *reinterpret_cast<const float4*>(bsum + c0 + j * 4);
    float x0 = t.x + b4.x, x1 = t.y + b4.y, x2 = t.z + b4.z, x3 = t.w + b4.w;
    v[j * 4 + 0] = x0; v[j * 4 + 1] = x1; v[j * 4 + 2] = x2; v[j * 4 + 3] = x3;
    sum += (x0 + x1) + (x2 + x3);
    sq = fmaf(x0, x0, sq); sq = fmaf(x1, x1, sq);
    sq = fmaf(x2, x2, sq); sq = fmaf(x3, x3, sq);
  }
  sum += __shfl_xor(sum, 16); sq += __shfl_xor(sq, 16);
  sum += __shfl_xor(sum, 32); sq += __shfl_xor(sq, 32);
  const float mean = sum * (1.f / 128.f);
  const float rstd = rsqrtf(sq * (1.f / 128.f) - mean * mean + LN_EPS);

  const int orow = r0 + lr;
  if (orow < nrows) {
    ushort* xo = Xout + (size_t)orow * HID + c0;
    uint pk[16];
#pragma unroll
    for (int j = 0; j < 8; j++) {
      float4 g4 = *reinterpret_cast<const float4*>(gamma + c0 + j * 4);
      float4 b4 = *reinterpret_cast<const float4*>(beta + c0 + j * 4);
      float o0 = fmaxf(fmaf((v[j * 4 + 0] - mean) * rstd, g4.x, b4.x), 0.f);
      float o1 = fmaxf(fmaf((v[j * 4 + 1] - mean) * rstd, g4.y, b4.y), 0.f);
      float o2 = fmaxf(fmaf((v[j * 4 + 2] - mean) * rstd, g4.z, b4.z), 0.f);
      float o3 = fmaxf(fmaf((v[j * 4 + 3] - mean) * rstd, g4.w, b4.w), 0.f);
      pk[j * 2 + 0] = (uint)f2bf(o0) | ((uint)f2bf(o1) << 16);
      pk[j * 2 + 1] = (uint)f2bf(o2) | ((uint)f2bf(o3) << 16);
    }
#pragma unroll
    for (int j = 0; j < 4; j++)
      *reinterpret_cast<uint4*>(xo + j * 8) =
          make_uint4(pk[j * 4 + 0], pk[j * 4 + 1], pk[j * 4 + 2], pk[j * 4 + 3]);
  }
}

// ---------------- JK sum: out = x1 + x2 + x3 (bf16 -> f32) ----------------
__global__ void k_jk(const ushort* __restrict__ a, const ushort* __restrict__ b,
                     const ushort* __restrict__ c, float* __restrict__ out, int total8) {
  int i = blockIdx.x * 256 + threadIdx.x;
  if (i >= total8) return;
  uint4 ua = *reinterpret_cast<const uint4*>(a + (size_t)i * 8);
  uint4 ub = *reinterpret_cast<const uint4*>(b + (size_t)i * 8);
  uint4 uc = *reinterpret_cast<const uint4*>(c + (size_t)i * 8);
  float o[8];
  const uint pa[4] = {ua.x, ua.y, ua.z, ua.w};
  const uint pb[4] = {ub.x, ub.y, ub.z, ub.w};
  const uint pc[4] = {uc.x, uc.y, uc.z, uc.w};
#pragma unroll
  for (int j = 0; j < 4; j++) {
    o[j * 2 + 0] = bf2f((ushort)(pa[j] & 0xffff)) + bf2f((ushort)(pb[j] & 0xffff)) +
                   bf2f((ushort)(pc[j] & 0xffff));
    o[j * 2 + 1] = bf2f((ushort)(pa[j] >> 16)) + bf2f((ushort)(pb[j] >> 16)) +
                   bf2f((ushort)(pc[j] >> 16));
  }
  float* op = out + (size_t)i * 8;
  *reinterpret_cast<float4*>(op) = make_float4(o[0], o[1], o[2], o[3]);
  *reinterpret_cast<float4*>(op + 4) = make_float4(o[4], o[5], o[6], o[7]);
}

// ---------------- launcher ----------------

extern "C" void kernel_launch(void* const* d_in, const int* in_sizes, int n_in,
                              void* d_out, int out_size, void* d_ws, size_t ws_size,
                              hipStream_t stream) {
  const float* x_in     = (const float*)d_in[0];
  const int*   edge     = (const int*)d_in[1];
  const float* lin_in_w = (const float*)d_in[2];
  const float* lin_in_b = (const float*)d_in[3];
  const float* conv_w   = (const float*)d_in[4];
  const float* conv_b   = (const float*)d_in[5];
  const float* lin_w    = (const float*)d_in[6];
  const float* lin_b    = (const float*)d_in[7];
  const float* ln_g     = (const float*)d_in[8];
  const float* ln_b     = (const float*)d_in[9];

  int N = in_sizes[0] / HID;
  int E = in_sizes[1] / 2;
  int L = in_sizes[4] / (HID * HID);

  const int* src = edge;
  const int* dst = edge + E;

  char* ws = (char*)d_ws;
  size_t off = 0;
  auto alloc = [&](size_t bytes) -> void* {
    void* p = (void*)(ws + off);
    off += (bytes + 255) & ~(size_t)255;
    return p;
  };
  int*    cnt       = (int*)alloc((size_t)N * 4);
  int*    cursor    = (int*)alloc((size_t)N * 4);
  int*    row_start = (int*)alloc((size_t)N * 4);
  float*  dinv      = (float*)alloc((size_t)N * 4);
  int*    blocksum  = (int*)alloc(4096);
  uint2*  rec       = (uint2*)alloc((size_t)E * 8);
  ushort* xb0       = (ushort*)alloc((size_t)N * HID * 2);
  ushort* xb1       = (ushort*)alloc((size_t)N * HID * 2);
  ushort* xb2       = (ushort*)alloc((size_t)N * HID * 2);
  ushort* sbuf      = (ushort*)alloc((size_t)N * HID * 2);
  ushort* wt_in     = (ushort*)alloc((size_t)128 * 128 * 2);
  ushort* wt_l      = (ushort*)alloc((size_t)L * 128 * 256 * 2);
  float*  bsum      = (float*)alloc((size_t)L * 128 * 4);
  (void)ws_size; (void)n_in; (void)out_size;

  int nb_n = (N + 255) / 256;
  int nb_e = (E + 255) / 256;
  int nbs  = (N + 511) / 512;
  int nb_g = (N + 63) / 64;
  int nb_w = (L * 128 * 256 + 255) / 256;
  int total8 = N * HID / 8;
  int nb_j = (total8 + 255) / 256;

  k_init<<<nb_n, 256, 0, stream>>>(cnt, cursor, N);
  k_count<<<nb_e, 256, 0, stream>>>(dst, cnt, E);
  k_dinv<<<nb_n, 256, 0, stream>>>(cnt, dinv, N);
  k_bsum<<<nbs, 256, 0, stream>>>(cnt, blocksum, N);
  k_bscan<<<1, 1024, 0, stream>>>(blocksum, nbs);
  k_rowstart<<<nbs, 256, 0, stream>>>(cnt, blocksum, row_start, N);
  k_scatter<<<nb_e, 256, 0, stream>>>(src, dst, row_start, cursor, dinv, rec, E);
  k_prep_w<<<nb_w, 256, 0, stream>>>(lin_in_w, conv_w, lin_w, conv_b, lin_b,
                                     wt_in, wt_l, bsum, L);

  k_gemm_in<<<nb_g, 256, 0, stream>>>(x_in, wt_in, lin_in_b, xb0, N);

  // rotate: layer i reads xprev, writes xcur; JK needs the 3 layer outputs
  ushort* xin_b[3]  = {xb0, xb1, xb2};
  ushort* xout_b[3] = {xb1, xb2, xb0};
  for (int i = 0; i < L; i++) {
    k_agg<<<(N + 3) / 4, 256, 0, stream>>>(xin_b[i], row_start, cnt, dinv, rec, sbuf, N);
    k_layer<<<nb_g, 256, 0, stream>>>(sbuf, xin_b[i], xout_b[i],
        wt_l + (size_t)i * 128 * 256, bsum + (size_t)i * 128,
        ln_g + (size_t)i * HID, ln_b + (size_t)i * HID, N);
  }
  k_jk<<<nb_j, 256, 0, stream>>>(xb1, xb2, xb0, (float*)d_out, total8);
}

// Round 5
// 360.333 us; speedup vs baseline: 2.2777x; 1.1319x over previous
//
#include <hip/hip_runtime.h>

#define HID 128
#define LN_EPS 1e-5f

typedef __attribute__((ext_vector_type(8))) short bf16x8;
typedef __attribute__((ext_vector_type(4))) float f32x4;

__device__ __forceinline__ ushort f2bf(float v) {
  union { float f; uint u; } x; x.f = v;
  uint r = x.u + 0x7fffu + ((x.u >> 16) & 1u);   // RNE
  return (ushort)(r >> 16);
}
__device__ __forceinline__ float bf2f(ushort u) {
  union { uint u; float f; } x; x.u = (uint)u << 16; return x.f;
}

// ---------------- graph preprocessing ----------------

__global__ void k_init(int* __restrict__ cnt, int n) {
  int i = blockIdx.x * 256 + threadIdx.x;
  if (i < n) cnt[i] = 0;
}

// counts AND records each edge's rank within its dst list (atomic return value)
__global__ void k_count(const int* __restrict__ dst, int* __restrict__ cnt,
                        int* __restrict__ rank, int E) {
  int e = blockIdx.x * 256 + threadIdx.x;
  if (e < E) rank[e] = atomicAdd(&cnt[dst[e]], 1);
}

__global__ void k_dinv(const int* __restrict__ cnt, float* __restrict__ dinv, int n) {
  int i = blockIdx.x * 256 + threadIdx.x;
  if (i < n) dinv[i] = rsqrtf((float)cnt[i] + 1.0f);   // +1 = self loop
}

// hierarchical exclusive scan of cnt -> row_start (512 elems per block)
__global__ void k_bsum(const int* __restrict__ cnt, int* __restrict__ bsum, int n) {
  __shared__ int red[256];
  int b = blockIdx.x, t = threadIdx.x;
  int i = b * 512 + t * 2;
  int s = ((i < n) ? cnt[i] : 0) + ((i + 1 < n) ? cnt[i + 1] : 0);
  red[t] = s;
  __syncthreads();
  for (int off = 128; off > 0; off >>= 1) {
    if (t < off) red[t] += red[t + off];
    __syncthreads();
  }
  if (t == 0) bsum[b] = red[0];
}

__global__ void k_bscan(int* __restrict__ bsum, int nb) {
  __shared__ int buf[1024];
  int t = threadIdx.x;
  int v = (t < nb) ? bsum[t] : 0;
  buf[t] = v;
  __syncthreads();
  for (int off = 1; off < 1024; off <<= 1) {
    int u = (t >= off) ? buf[t - off] : 0;
    __syncthreads();
    buf[t] += u;
    __syncthreads();
  }
  if (t < nb) bsum[t] = buf[t] - v;   // exclusive
}

__global__ void k_rowstart(const int* __restrict__ cnt, const int* __restrict__ bsum,
                           int* __restrict__ row_start, int n) {
  __shared__ int buf[256];
  int b = blockIdx.x, t = threadIdx.x;
  int i = b * 512 + t * 2;
  int c0 = (i < n) ? cnt[i] : 0;
  int c1 = (i + 1 < n) ? cnt[i + 1] : 0;
  int s = c0 + c1;
  buf[t] = s;
  __syncthreads();
  int mine = s;
  for (int off = 1; off < 256; off <<= 1) {
    int u = (t >= off) ? buf[t - off] : 0;
    __syncthreads();
    buf[t] += u;
    __syncthreads();
  }
  int ex = buf[t] - mine + bsum[b];
  if (i < n) row_start[i] = ex;
  if (i + 1 < n) row_start[i + 1] = ex + c0;
}

// atomic-free scatter: one 8B record per edge at row_start[dst] + rank[e]
__global__ void k_scatter(const int* __restrict__ src, const int* __restrict__ dst,
                          const int* __restrict__ row_start, const int* __restrict__ rank,
                          const float* __restrict__ dinv,
                          uint2* __restrict__ rec, int E) {
  int e = blockIdx.x * 256 + threadIdx.x;
  if (e < E) {
    int d = dst[e], s = src[e];
    int pos = row_start[d] + rank[e];
    union { float f; uint u; } w; w.f = dinv[s] * dinv[d];
    rec[pos] = make_uint2((uint)s, w.u);
  }
}

// ---------------- weight prep: bf16, MFMA-fragment-ordered ----------------
// Fragment layout: frag[(n*KS + ks)*512 + lane*8 + j] = W^T-element for
//   k = ks*32 + (lane>>4)*8 + j,  col = n*16 + (lane&15)
__global__ void k_prep_w(const float* __restrict__ lin_in_w,
                         const float* __restrict__ conv_w, const float* __restrict__ lin_w,
                         const float* __restrict__ conv_b, const float* __restrict__ lin_b,
                         ushort* __restrict__ wt_in, ushort* __restrict__ wt_l,
                         float* __restrict__ bsum, int L) {
  int tid = blockIdx.x * 256 + threadIdx.x;
  int total = L * 128 * 256;
  if (tid < total) {
    int l = tid >> 15;              // /32768
    int idx = tid & 32767;
    int n = idx >> 12;              // 8 col-blocks
    int r = idx & 4095;
    int ks = r >> 9;                // 8 k-steps (K=256)
    int r2 = r & 511;
    int lane = r2 >> 3;
    int j = r2 & 7;
    int k2 = ks * 32 + (lane >> 4) * 8 + j;
    int c = n * 16 + (lane & 15);
    float v = (k2 < 128) ? conv_w[((size_t)l * 128 + k2) * 128 + c]
                         : lin_w[((size_t)l * 128 + (k2 - 128)) * 128 + c];
    wt_l[tid] = f2bf(v);
  }
  if (tid < 128 * 128) {
    int n = tid >> 11;              // 8 col-blocks
    int r = tid & 2047;
    int ks = r >> 9;                // 4 k-steps (K=128)
    int r2 = r & 511;
    int lane = r2 >> 3;
    int j = r2 & 7;
    int k = ks * 32 + (lane >> 4) * 8 + j;
    int c = n * 16 + (lane & 15);
    wt_in[tid] = f2bf(lin_in_w[k * 128 + c]);
  }
  if (tid < L * 128) bsum[tid] = conv_b[tid] + lin_b[tid];
}

// ---------------- aggregation: s = D^-1/2 (A+I) D^-1/2 x  (bf16 in/out) ----------------
// one wave per node; 4-deep unrolled gather loop, tail-free (clamped index, zeroed weight)
__global__ void k_agg(const ushort* __restrict__ X, const int* __restrict__ row_start,
                      const int* __restrict__ cnt, const float* __restrict__ dinv,
                      const uint2* __restrict__ rec, ushort* __restrict__ Sout, int n) {
  int node = blockIdx.x * 4 + (threadIdx.x >> 6);
  if (node >= n) return;
  int lane = threadIdx.x & 63;
  float dv = dinv[node];
  uint v = *reinterpret_cast<const uint*>(X + (size_t)node * HID + lane * 2);
  float ax = dv * dv * bf2f((ushort)(v & 0xffff));
  float ay = dv * dv * bf2f((ushort)(v >> 16));
  int start = row_start[node];
  int m = cnt[node];
  int last = start + m - 1;
  for (int e = 0; e < m; e += 4) {
    int i0 = start + e;
    // all 4 rec loads + all 4 row gathers issued unconditionally -> 4 in flight
    uint2 r0 = rec[i0];
    uint2 r1 = rec[min(i0 + 1, last)];
    uint2 r2 = rec[min(i0 + 2, last)];
    uint2 r3 = rec[min(i0 + 3, last)];
    uint u0 = *reinterpret_cast<const uint*>(X + (size_t)r0.x * HID + lane * 2);
    uint u1 = *reinterpret_cast<const uint*>(X + (size_t)r1.x * HID + lane * 2);
    uint u2 = *reinterpret_cast<const uint*>(X + (size_t)r2.x * HID + lane * 2);
    uint u3 = *reinterpret_cast<const uint*>(X + (size_t)r3.x * HID + lane * 2);
    union { uint u; float f; } w0, w1, w2, w3;
    w0.u = r0.y;
    w1.u = (e + 1 < m) ? r1.y : 0u;
    w2.u = (e + 2 < m) ? r2.y : 0u;
    w3.u = (e + 3 < m) ? r3.y : 0u;
    ax = fmaf(w0.f, bf2f((ushort)(u0 & 0xffff)), ax);
    ay = fmaf(w0.f, bf2f((ushort)(u0 >> 16)), ay);
    ax = fmaf(w1.f, bf2f((ushort)(u1 & 0xffff)), ax);
    ay = fmaf(w1.f, bf2f((ushort)(u1 >> 16)), ay);
    ax = fmaf(w2.f, bf2f((ushort)(u2 & 0xffff)), ax);
    ay = fmaf(w2.f, bf2f((ushort)(u2 >> 16)), ay);
    ax = fmaf(w3.f, bf2f((ushort)(u3 & 0xffff)), ax);
    ay = fmaf(w3.f, bf2f((ushort)(u3 >> 16)), ay);
  }
  uint o = (uint)f2bf(ax) | ((uint)f2bf(ay) << 16);
  *reinterpret_cast<uint*>(Sout + (size_t)node * HID + lane * 2) = o;
}

// ---------------- MFMA GEMM kernels ----------------
// per block: 4 waves, 16 rows each; per wave: full 128 output cols.
// A-frag: lane holds A[r0 + (l&15)][ks*32 + (l>>4)*8 .. +7]
// B-frag: coalesced from fragment-ordered WtF
// C: row=(l>>4)*4+q, col=n*16+(l&15) -> LDS transpose for coalesced epilogue

__global__ void __launch_bounds__(256, 2)
k_gemm_in(const float* __restrict__ Xin, const ushort* __restrict__ WtF,
          const float* __restrict__ bias, ushort* __restrict__ Xout, int nrows) {
  __shared__ float lds[4 * 16 * 132];
  const int tid = threadIdx.x;
  const int wid = tid >> 6, lane = tid & 63;
  const int lr = lane & 15, lg = lane >> 4;
  const int r0 = blockIdx.x * 64 + wid * 16;
  const int arow = r0 + lr;
  const bool rowok = arow < nrows;

  bf16x8 a[4];
  {
    const float* xp = Xin + (size_t)arow * HID + lg * 8;
#pragma unroll
    for (int ks = 0; ks < 4; ks++) {
      bf16x8 t;
#pragma unroll
      for (int i = 0; i < 8; i++) t[i] = 0;
      if (rowok) {
        float4 u0 = *reinterpret_cast<const float4*>(xp + ks * 32);
        float4 u1 = *reinterpret_cast<const float4*>(xp + ks * 32 + 4);
        t[0] = (short)f2bf(u0.x); t[1] = (short)f2bf(u0.y);
        t[2] = (short)f2bf(u0.z); t[3] = (short)f2bf(u0.w);
        t[4] = (short)f2bf(u1.x); t[5] = (short)f2bf(u1.y);
        t[6] = (short)f2bf(u1.z); t[7] = (short)f2bf(u1.w);
      }
      a[ks] = t;
    }
  }

  f32x4 acc[8];
#pragma unroll
  for (int n = 0; n < 8; n++) acc[n] = f32x4{0.f, 0.f, 0.f, 0.f};

  const ushort* wb = WtF + lane * 8;
#pragma unroll
  for (int n = 0; n < 8; n++)
#pragma unroll
    for (int ks = 0; ks < 4; ks++) {
      bf16x8 b = *reinterpret_cast<const bf16x8*>(wb + (n * 4 + ks) * 512);
      acc[n] = __builtin_amdgcn_mfma_f32_16x16x32_bf16(a[ks], b, acc[n], 0, 0, 0);
    }

  float* T = lds + wid * (16 * 132);
#pragma unroll
  for (int n = 0; n < 8; n++)
#pragma unroll
    for (int q = 0; q < 4; q++)
      T[(lg * 4 + q) * 132 + n * 16 + lr] = acc[n][q];

  const int c0 = lg * 32;
  const float* Trow = T + lr * 132 + c0;
  const int orow = r0 + lr;
  if (orow < nrows) {
    ushort* xo = Xout + (size_t)orow * HID + c0;
    uint pk[16];
#pragma unroll
    for (int j = 0; j < 8; j++) {
      float4 t = *reinterpret_cast<const float4*>(Trow + j * 4);
      float4 b4 = *reinterpret_cast<const float4*>(bias + c0 + j * 4);
      float o0 = t.x + b4.x, o1 = t.y + b4.y, o2 = t.z + b4.z, o3 = t.w + b4.w;
      pk[j * 2 + 0] = (uint)f2bf(o0) | ((uint)f2bf(o1) << 16);
      pk[j * 2 + 1] = (uint)f2bf(o2) | ((uint)f2bf(o3) << 16);
    }
#pragma unroll
    for (int j = 0; j < 4; j++)
      *reinterpret_cast<uint4*>(xo + j * 8) =
          make_uint4(pk[j * 4 + 0], pk[j * 4 + 1], pk[j * 4 + 2], pk[j * 4 + 3]);
  }
}

__global__ void __launch_bounds__(256, 2)
k_layer(const ushort* __restrict__ S, const ushort* __restrict__ Xin,
        ushort* __restrict__ Xout,
        const ushort* __restrict__ WtF, const float* __restrict__ bsum,
        const float* __restrict__ gamma, const float* __restrict__ beta, int nrows) {
  __shared__ float lds[4 * 16 * 132];
  const int tid = threadIdx.x;
  const int wid = tid >> 6, lane = tid & 63;
  const int lr = lane & 15, lg = lane >> 4;
  const int r0 = blockIdx.x * 64 + wid * 16;
  const int arow = r0 + lr;
  const bool rowok = arow < nrows;

  bf16x8 a[8];
  {
    const ushort* sp = S + (size_t)arow * HID + lg * 8;
    const ushort* xp = Xin + (size_t)arow * HID + lg * 8;
    bf16x8 z;
#pragma unroll
    for (int i = 0; i < 8; i++) z[i] = 0;
#pragma unroll
    for (int ks = 0; ks < 4; ks++)
      a[ks] = rowok ? *reinterpret_cast<const bf16x8*>(sp + ks * 32) : z;
#pragma unroll
    for (int ks = 0; ks < 4; ks++)
      a[4 + ks] = rowok ? *reinterpret_cast<const bf16x8*>(xp + ks * 32) : z;
  }

  f32x4 acc[8];
#pragma unroll
  for (int n = 0; n < 8; n++) acc[n] = f32x4{0.f, 0.f, 0.f, 0.f};

  const ushort* wb = WtF + lane * 8;
#pragma unroll
  for (int n = 0; n < 8; n++)
#pragma unroll
    for (int ks = 0; ks < 8; ks++) {
      bf16x8 b = *reinterpret_cast<const bf16x8*>(wb + (n * 8 + ks) * 512);
      acc[n] = __builtin_amdgcn_mfma_f32_16x16x32_bf16(a[ks], b, acc[n], 0, 0, 0);
    }

  float* T = lds + wid * (16 * 132);
#pragma unroll
  for (int n = 0; n < 8; n++)
#pragma unroll
    for (int q = 0; q < 4; q++)
      T[(lg * 4 + q) * 132 + n * 16 + lr] = acc[n][q];

  // epilogue: lane handles row lr, cols [c0, c0+32)
  const int c0 = lg * 32;
  const float* Trow = T + lr * 132 + c0;
  float v[32];
  float sum = 0.f, sq = 0.f;
#pragma unroll
  for (int j = 0; j < 8; j++) {
    float4 t = *reinterpret_cast<const float4*>(Trow + j * 4);
    float4 b4 = *reinterpret_cast<const float4*>(bsum + c0 + j * 4);
    float x0 = t.x + b4.x, x1 = t.y + b4.y, x2 = t.z + b4.z, x3 = t.w + b4.w;
    v[j * 4 + 0] = x0; v[j * 4 + 1] = x1; v[j * 4 + 2] = x2; v[j * 4 + 3] = x3;
    sum += (x0 + x1) + (x2 + x3);
    sq = fmaf(x0, x0, sq); sq = fmaf(x1, x1, sq);
    sq = fmaf(x2, x2, sq); sq = fmaf(x3, x3, sq);
  }
  sum += __shfl_xor(sum, 16); sq += __shfl_xor(sq, 16);
  sum += __shfl_xor(sum, 32); sq += __shfl_xor(sq, 32);
  const float mean = sum * (1.f / 128.f);
  const float rstd = rsqrtf(sq * (1.f / 128.f) - mean * mean + LN_EPS);

  const int orow = r0 + lr;
  if (orow < nrows) {
    ushort* xo = Xout + (size_t)orow * HID + c0;
    uint pk[16];
#pragma unroll
    for (int j = 0; j < 8; j++) {
      float4 g4 = *reinterpret_cast<const float4*>(gamma + c0 + j * 4);
      float4 b4 = *reinterpret_cast<const float4*>(beta + c0 + j * 4);
      float o0 = fmaxf(fmaf((v[j * 4 + 0] - mean) * rstd, g4.x, b4.x), 0.f);
      float o1 = fmaxf(fmaf((v[j * 4 + 1] - mean) * rstd, g4.y, b4.y), 0.f);
      float o2 = fmaxf(fmaf((v[j * 4 + 2] - mean) * rstd, g4.z, b4.z), 0.f);
      float o3 = fmaxf(fmaf((v[j * 4 + 3] - mean) * rstd, g4.w, b4.w), 0.f);
      pk[j * 2 + 0] = (uint)f2bf(o0) | ((uint)f2bf(o1) << 16);
      pk[j * 2 + 1] = (uint)f2bf(o2) | ((uint)f2bf(o3) << 16);
    }
#pragma unroll
    for (int j = 0; j < 4; j++)
      *reinterpret_cast<uint4*>(xo + j * 8) =
          make_uint4(pk[j * 4 + 0], pk[j * 4 + 1], pk[j * 4 + 2], pk[j * 4 + 3]);
  }
}

// ---------------- JK sum: out = x1 + x2 + x3 (bf16 -> f32) ----------------
__global__ void k_jk(const ushort* __restrict__ a, const ushort* __restrict__ b,
                     const ushort* __restrict__ c, float* __restrict__ out, int total8) {
  int i = blockIdx.x * 256 + threadIdx.x;
  if (i >= total8) return;
  uint4 ua = *reinterpret_cast<const uint4*>(a + (size_t)i * 8);
  uint4 ub = *reinterpret_cast<const uint4*>(b + (size_t)i * 8);
  uint4 uc = *reinterpret_cast<const uint4*>(c + (size_t)i * 8);
  float o[8];
  const uint pa[4] = {ua.x, ua.y, ua.z, ua.w};
  const uint pb[4] = {ub.x, ub.y, ub.z, ub.w};
  const uint pc[4] = {uc.x, uc.y, uc.z, uc.w};
#pragma unroll
  for (int j = 0; j < 4; j++) {
    o[j * 2 + 0] = bf2f((ushort)(pa[j] & 0xffff)) + bf2f((ushort)(pb[j] & 0xffff)) +
                   bf2f((ushort)(pc[j] & 0xffff));
    o[j * 2 + 1] = bf2f((ushort)(pa[j] >> 16)) + bf2f((ushort)(pb[j] >> 16)) +
                   bf2f((ushort)(pc[j] >> 16));
  }
  float* op = out + (size_t)i * 8;
  *reinterpret_cast<float4*>(op) = make_float4(o[0], o[1], o[2], o[3]);
  *reinterpret_cast<float4*>(op + 4) = make_float4(o[4], o[5], o[6], o[7]);
}

// ---------------- launcher ----------------

extern "C" void kernel_launch(void* const* d_in, const int* in_sizes, int n_in,
                              void* d_out, int out_size, void* d_ws, size_t ws_size,
                              hipStream_t stream) {
  const float* x_in     = (const float*)d_in[0];
  const int*   edge     = (const int*)d_in[1];
  const float* lin_in_w = (const float*)d_in[2];
  const float* lin_in_b = (const float*)d_in[3];
  const float* conv_w   = (const float*)d_in[4];
  const float* conv_b   = (const float*)d_in[5];
  const float* lin_w    = (const float*)d_in[6];
  const float* lin_b    = (const float*)d_in[7];
  const float* ln_g     = (const float*)d_in[8];
  const float* ln_b     = (const float*)d_in[9];

  int N = in_sizes[0] / HID;
  int E = in_sizes[1] / 2;
  int L = in_sizes[4] / (HID * HID);

  const int* src = edge;
  const int* dst = edge + E;

  char* ws = (char*)d_ws;
  size_t off = 0;
  auto alloc = [&](size_t bytes) -> void* {
    void* p = (void*)(ws + off);
    off += (bytes + 255) & ~(size_t)255;
    return p;
  };
  int*    cnt       = (int*)alloc((size_t)N * 4);
  int*    rank      = (int*)alloc((size_t)E * 4);
  int*    row_start = (int*)alloc((size_t)N * 4);
  float*  dinv      = (float*)alloc((size_t)N * 4);
  int*    blocksum  = (int*)alloc(4096);
  uint2*  rec       = (uint2*)alloc((size_t)E * 8);
  ushort* xb0       = (ushort*)alloc((size_t)N * HID * 2);
  ushort* xb1       = (ushort*)alloc((size_t)N * HID * 2);
  ushort* xb2       = (ushort*)alloc((size_t)N * HID * 2);
  ushort* sbuf      = (ushort*)alloc((size_t)N * HID * 2);
  ushort* wt_in     = (ushort*)alloc((size_t)128 * 128 * 2);
  ushort* wt_l      = (ushort*)alloc((size_t)L * 128 * 256 * 2);
  float*  bsum      = (float*)alloc((size_t)L * 128 * 4);
  (void)ws_size; (void)n_in; (void)out_size;

  int nb_n = (N + 255) / 256;
  int nb_e = (E + 255) / 256;
  int nbs  = (N + 511) / 512;
  int nb_g = (N + 63) / 64;
  int nb_w = (L * 128 * 256 + 255) / 256;
  int total8 = N * HID / 8;
  int nb_j = (total8 + 255) / 256;

  k_init<<<nb_n, 256, 0, stream>>>(cnt, N);
  k_count<<<nb_e, 256, 0, stream>>>(dst, cnt, rank, E);
  k_dinv<<<nb_n, 256, 0, stream>>>(cnt, dinv, N);
  k_bsum<<<nbs, 256, 0, stream>>>(cnt, blocksum, N);
  k_bscan<<<1, 1024, 0, stream>>>(blocksum, nbs);
  k_rowstart<<<nbs, 256, 0, stream>>>(cnt, blocksum, row_start, N);
  k_scatter<<<nb_e, 256, 0, stream>>>(src, dst, row_start, rank, dinv, rec, E);
  k_prep_w<<<nb_w, 256, 0, stream>>>(lin_in_w, conv_w, lin_w, conv_b, lin_b,
                                     wt_in, wt_l, bsum, L);

  k_gemm_in<<<nb_g, 256, 0, stream>>>(x_in, wt_in, lin_in_b, xb0, N);

  // rotate: layer i reads xprev, writes xcur; JK needs the 3 layer outputs
  ushort* xin_b[3]  = {xb0, xb1, xb2};
  ushort* xout_b[3] = {xb1, xb2, xb0};
  for (int i = 0; i < L; i++) {
    k_agg<<<(N + 3) / 4, 256, 0, stream>>>(xin_b[i], row_start, cnt, dinv, rec, sbuf, N);
    k_layer<<<nb_g, 256, 0, stream>>>(sbuf, xin_b[i], xout_b[i],
        wt_l + (size_t)i * 128 * 256, bsum + (size_t)i * 128,
        ln_g + (size_t)i * HID, ln_b + (size_t)i * HID, N);
  }
  k_jk<<<nb_j, 256, 0, stream>>>(xb1, xb2, xb0, (float*)d_out, total8);
}